// Round 6
// baseline (182.294 us; speedup 1.0000x reference)
//
#include <hip/hip_runtime.h>
#include <math.h>

#define BS 32
#define NQ 900
#define NC 1203
#define NT 100
#define SLOTS 15   // ceil(900/64)

// ---------------------------------------------------------------------------
// Kernel 1: cost matrix (math identical to passing rounds) + optional CT.
// ---------------------------------------------------------------------------
__global__ __launch_bounds__(128) void cost_kernel(
    const float* __restrict__ logits, const float* __restrict__ boxes,
    const int* __restrict__ tlabels, const float* __restrict__ tboxes,
    float* __restrict__ C, float* __restrict__ CT)
{
    int bq = blockIdx.x;
    int b = bq / NQ, q = bq % NQ;
    int t = threadIdx.x;

    const float* pb = boxes + (size_t)(b * NQ + q) * 4;
    float pcx = pb[0], pcy = pb[1], pw = pb[2], ph = pb[3];

    if (t < NT) {
        int id = tlabels[b * NT + t];
        float x = logits[(size_t)(b * NQ + q) * NC + id];
        float prob = 1.0f / (1.0f + expf(-x));
        float neg = 0.75f * (prob * prob) * (-logf(1.0f - prob + 1e-8f));
        float pos = 0.25f * ((1.0f - prob) * (1.0f - prob)) * (-logf(prob + 1e-8f));
        float cclass = pos - neg;

        const float* tb = tboxes + (size_t)(b * NT + t) * 4;
        float tcx = tb[0], tcy = tb[1], tw = tb[2], th = tb[3];
        float cbbox = fabsf(pcx - tcx) + fabsf(pcy - tcy) + fabsf(pw - tw) + fabsf(ph - th);

        float p0 = pcx - 0.5f * pw, p1 = pcy - 0.5f * ph;
        float p2 = pcx + 0.5f * pw, p3 = pcy + 0.5f * ph;
        float t0 = tcx - 0.5f * tw, t1 = tcy - 0.5f * th;
        float t2 = tcx + 0.5f * tw, t3 = tcy + 0.5f * th;
        float area1 = (p2 - p0) * (p3 - p1);
        float area2 = (t2 - t0) * (t3 - t1);
        float ltx = fmaxf(p0, t0), lty = fmaxf(p1, t1);
        float rbx = fminf(p2, t2), rby = fminf(p3, t3);
        float wx = fmaxf(rbx - ltx, 0.0f), wy = fmaxf(rby - lty, 0.0f);
        float inter = wx * wy;
        float uni = area1 + area2 - inter;
        float iou = inter / uni;
        float l2x = fminf(p0, t0), l2y = fminf(p1, t1);
        float r2x = fmaxf(p2, t2), r2y = fmaxf(p3, t3);
        float hx = fmaxf(r2x - l2x, 0.0f), hy = fmaxf(r2y - l2y, 0.0f);
        float hull = hx * hy;
        float giou = iou - (hull - uni) / hull;

        float val = 5.0f * cbbox + 2.0f * cclass + 2.0f * (-giou);
        C[(size_t)(b * NQ + q) * NT + t] = val;
        if (CT) CT[((size_t)b * NT + t) * NQ + q] = val;
    }
}

// ---------------------------------------------------------------------------
// Kernel 2: per-row min+argmin of cost.T reading C DIRECTLY (no CT needed).
// One 256-thread block per (b,t); strided reads, latency hidden by 3200-block
// TLP. Results stashed in the pred/tgt output region (overwritten later).
// ---------------------------------------------------------------------------
__global__ __launch_bounds__(256) void rowmin2_kernel(
    const float* __restrict__ C, float* __restrict__ u0, int* __restrict__ amin)
{
    int bi = blockIdx.x;                    // b*NT + t
    int b = bi / NT, t = bi % NT;
    const float* Cbt = C + (size_t)b * NQ * NT + t;   // element q at Cbt[q*NT]
    int tid = threadIdx.x;
    int w = tid >> 6, lane = tid & 63;

    float best = __builtin_huge_valf();
    int bq = NQ;
    for (int q = tid; q < NQ; q += 256) {   // ascending per thread -> strict < keeps smallest q
        float c = Cbt[(size_t)q * NT];
        if (c < best) { best = c; bq = q; }
    }
    for (int off = 32; off; off >>= 1) {
        float ov = __shfl_down(best, off);
        int  oq = __shfl_down(bq, off);
        if (ov < best || (ov == best && oq < bq)) { best = ov; bq = oq; }
    }
    __shared__ float sv[4];
    __shared__ int sj[4];
    if (lane == 0) { sv[w] = best; sj[w] = bq; }
    __syncthreads();
    if (tid == 0) {
        float bv = sv[0]; int bj = sj[0];
        for (int k = 1; k < 4; ++k) {
            if (sv[k] < bv || (sv[k] == bv && sj[k] < bj)) { bv = sv[k]; bj = sj[k]; }
        }
        u0[bi] = bv; amin[bi] = bj;
    }
}

// ---------------------------------------------------------------------------
// Kernel 3: JV solver, one wave per batch. Always consumes the rowmin stash.
// B: greedy claim  C: ARR with 2-visit cap  D: deferred-dual Dijkstra.
// Exact LSA optimum == reference (optimum unique for continuous random costs).
// ---------------------------------------------------------------------------
template<bool USE_CT>
__global__ __launch_bounds__(64) void jv_kernel(
    const float* __restrict__ C, const float* __restrict__ CT,
    const float* __restrict__ u0g, const int* __restrict__ aming,
    float* __restrict__ pred_out, float* __restrict__ tgt_out)
{
    int b = blockIdx.x;
    const float* Cb  = C + (size_t)b * NQ * NT;
    const float* CTb = USE_CT ? CT + (size_t)b * NT * NQ : nullptr;
    int lane = threadIdx.x;
    const double INF = __builtin_huge_val();

    __shared__ double u[NT];
    __shared__ double vsh[NQ];
    __shared__ double spsh[NQ];
    __shared__ int path[NQ];
    __shared__ int row4col[NQ];
    __shared__ int col4row[NT];
    __shared__ int aminsh[NT];
    __shared__ int freeRows[NT + 4];
    __shared__ int parked[NT];
    __shared__ int srList[136];
    __shared__ unsigned char visits[NT];
    __shared__ int nFreeSh, nParkSh;

    // ---- phase A: init from stash ----
    for (int j = lane; j < NQ; j += 64) { vsh[j] = 0.0; row4col[j] = 0x7fffffff; }
    for (int i = lane; i < NT; i += 64) {
        visits[i] = 0;
        u[i] = (double)u0g[b * NT + i];
        aminsh[i] = aming[b * NT + i];
    }
    if (lane == 0) { nFreeSh = 0; nParkSh = 0; }
    __syncthreads();

    // ---- phase B: greedy claim (smallest row wins a contested column) ----
    for (int i = lane; i < NT; i += 64) atomicMin(&row4col[aminsh[i]], i);
    __syncthreads();
    if (lane == 0) {
        int n = 0;
        for (int i = 0; i < NT; ++i) {
            int j = aminsh[i];
            if (row4col[j] == i) col4row[i] = j;
            else { col4row[i] = -1; freeRows[n++] = i; }
        }
        nFreeSh = n;
    }
    __syncthreads();
    for (int j = lane; j < NQ; j += 64)
        if (row4col[j] == 0x7fffffff) row4col[j] = -1;
    __syncthreads();

    // ---- phase C: ARR with 2-visit cap ----
    int guard = 0;
    while (guard++ < 300) {
        int nf = nFreeSh;                          // uniform
        if (nf == 0) break;
        int i = freeRows[nf - 1];                  // uniform
        if (visits[i] >= 2) {                      // park for Dijkstra
            if (lane == 0) { nFreeSh = nf - 1; parked[nParkSh] = i; nParkSh++; }
            __syncthreads();
            continue;
        }
        if (lane == 0) visits[i]++;

        const float* rowp = USE_CT ? (CTb + (size_t)i * NQ) : nullptr;
        double m1 = INF, m2 = INF; int j1 = 0;
        #pragma unroll
        for (int k = 0; k < SLOTS; ++k) {
            int j = (k << 6) + lane;
            if ((k < SLOTS - 1) || (j < NQ)) {
                float c = USE_CT ? rowp[j] : Cb[(size_t)j * NT + i];
                double cur = (double)c - vsh[j];
                if (cur < m1) { m2 = m1; m1 = cur; j1 = j; }
                else if (cur < m2) m2 = cur;
            }
        }
        for (int off = 32; off; off >>= 1) {
            double o1 = __shfl_down(m1, off); int oj = __shfl_down(j1, off);
            double o2 = __shfl_down(m2, off);
            if (o1 < m1 || (o1 == m1 && oj < j1)) { m2 = fmin(m1, o2); m1 = o1; j1 = oj; }
            else m2 = fmin(m2, o1);
        }
        if (lane == 0) {
            u[i] = m2;
            vsh[j1] -= (m2 - m1);
            int inc = row4col[j1];
            row4col[j1] = i; col4row[i] = j1;
            int n = nf - 1;
            if (inc >= 0) { col4row[inc] = -1; freeRows[n++] = inc; }
            nFreeSh = n;
        }
        __syncthreads();
    }
    // spill anything left to parked
    if (lane == 0) {
        while (nFreeSh > 0) { nFreeSh--; parked[nParkSh] = freeRows[nFreeSh]; nParkSh++; }
    }
    __syncthreads();

    // ---- phase D: deferred-dual Dijkstra (scipy-style) for parked rows ----
    int np = nParkSh;
    for (int f = 0; f < np; ++f) {
        int curRow = parked[f];
        double minv[SLOTS];
        #pragma unroll
        for (int k = 0; k < SLOTS; ++k) minv[k] = INF;
        unsigned scMask = 0;
        double minVal = 0.0;
        int i = curRow, nIter = 0, sink = -1;

        while (sink < 0) {
            if (lane == 0) srList[nIter] = i;
            double ui = u[i];
            const float* rowp = USE_CT ? (CTb + (size_t)i * NQ) : nullptr;
            double lbest = INF; int lbestj = 0x7fffffff;
            #pragma unroll
            for (int k = 0; k < SLOTS; ++k) {
                int j = (k << 6) + lane;
                bool ok = (k < SLOTS - 1) || (j < NQ);
                if (ok && !((scMask >> k) & 1u)) {
                    float c = USE_CT ? rowp[j] : Cb[(size_t)j * NT + i];
                    double cur = minVal + (double)c - ui - vsh[j];
                    if (cur < minv[k]) { minv[k] = cur; spsh[j] = cur; path[j] = i; }
                    double mk = minv[k];
                    if (mk < lbest || (mk == lbest && j < lbestj)) { lbest = mk; lbestj = j; }
                }
            }
            for (int off = 32; off; off >>= 1) {
                double ov = __shfl_down(lbest, off);
                int  oj = __shfl_down(lbestj, off);
                if (ov < lbest || (ov == lbest && oj < lbestj)) { lbest = ov; lbestj = oj; }
            }
            minVal = __shfl(lbest, 0);
            int j1 = __shfl(lbestj, 0);
            if (lane == (j1 & 63)) scMask |= (1u << (j1 >> 6));
            int r = row4col[j1];
            nIter++;
            if (r < 0 || nIter >= 127) sink = j1;
            else i = r;
        }
        __syncthreads();   // spsh/path stable before dual updates

        if (lane == 0) {
            u[curRow] += minVal;
            for (int t2 = 1; t2 < nIter; ++t2) {
                int ri = srList[t2];
                u[ri] += minVal - spsh[col4row[ri]];   // pre-augment col4row
            }
        }
        #pragma unroll
        for (int k = 0; k < SLOTS; ++k) {
            int j = (k << 6) + lane;
            bool ok = (k < SLOTS - 1) || (j < NQ);
            if (ok && ((scMask >> k) & 1u)) vsh[j] -= minVal - minv[k];
        }
        if (lane == 0) {   // augment
            int j = sink, g2 = 0;
            while (g2++ < 128) {
                int ri = path[j];
                row4col[j] = ri;
                int t2 = col4row[ri]; col4row[ri] = j;
                j = t2;
                if (ri == curRow) break;
            }
        }
        __syncthreads();
    }

    // ---- epilogue: rank-sort col4row, write indices ----
    for (int i2 = lane; i2 < NT; i2 += 64) {
        int ci = col4row[i2];
        int rank = 0;
        for (int k2 = 0; k2 < NT; ++k2) rank += (col4row[k2] < ci);
        pred_out[b * NT + rank] = (float)ci;
        tgt_out[b * NT + rank] = (float)i2;
    }
}

extern "C" void kernel_launch(void* const* d_in, const int* in_sizes, int n_in,
                              void* d_out, int out_size, void* d_ws, size_t ws_size,
                              hipStream_t stream) {
    const float* logits = (const float*)d_in[0];
    const float* boxes  = (const float*)d_in[1];
    const int*   tlab   = (const int*)d_in[2];
    const float* tboxes = (const float*)d_in[3];

    float* out  = (float*)d_out;
    float* C    = out;                                  // 32*900*100
    float* pred = out + (size_t)BS * NQ * NT;           // 32*100
    float* tgt  = pred + BS * NT;                       // 32*100

    const size_t ctBytes = (size_t)BS * NT * NQ * sizeof(float);
    float* CT = (ws_size >= ctBytes) ? (float*)d_ws : nullptr;

    cost_kernel<<<BS * NQ, 128, 0, stream>>>(logits, boxes, tlab, tboxes, C, CT);

    // ws-independent parallel row-min; stash in pred/tgt region (jv overwrites)
    float* u0 = pred;          // 3200 floats
    int* amin = (int*)tgt;     // 3200 ints
    rowmin2_kernel<<<BS * NT, 256, 0, stream>>>(C, u0, amin);

    if (CT) jv_kernel<true ><<<BS, 64, 0, stream>>>(C, CT, u0, amin, pred, tgt);
    else    jv_kernel<false><<<BS, 64, 0, stream>>>(C, nullptr, u0, amin, pred, tgt);
}